// Round 5
// baseline (584.300 us; speedup 1.0000x reference)
//
#include <hip/hip_runtime.h>
#include <math.h>

typedef short short8 __attribute__((ext_vector_type(8)));
typedef float float4v __attribute__((ext_vector_type(4)));
#define AS1 __attribute__((address_space(1)))
#define AS3 __attribute__((address_space(3)))

__device__ __forceinline__ float b2f(ushort u) {
    unsigned v = ((unsigned)u) << 16; float f; __builtin_memcpy(&f, &v, 4); return f;
}
__device__ __forceinline__ ushort f2b(float f) {
    unsigned v; __builtin_memcpy(&v, &f, 4);
    unsigned r = (v + 0x7fffu + ((v >> 16) & 1u)) >> 16;
    return (ushort)r;
}

// ---------- fp32 -> bf16 convert (optional zero-pad rows) ----------
__global__ void cvt_pad(const float* __restrict__ src, ushort* __restrict__ dst,
                        int src_rows, int cols, int total4) {
    int i = blockIdx.x * 256 + threadIdx.x;
    if (i >= total4) return;
    size_t e = (size_t)i * 4;
    int r = (int)(e / (size_t)cols);
    ushort4 o;
    if (r < src_rows) {
        float4 v = *(const float4*)(src + e);
        o.x = f2b(v.x); o.y = f2b(v.y); o.z = f2b(v.z); o.w = f2b(v.w);
    } else {
        o.x = 0; o.y = 0; o.z = 0; o.w = 0;
    }
    *(ushort4*)(dst + e) = o;
}

// ---------- bf16 GEMM: C(MxN) = A(MxK) @ B(NxK)^T, strided ----------
__global__ __launch_bounds__(256)
void gemm_bt(const ushort* __restrict__ A, const ushort* __restrict__ B,
             void* __restrict__ Cv, int K, int lda, int ldb, int ldc, int f32out) {
    __shared__ ushort sA[128 * 32];
    __shared__ ushort sB[128 * 32];
    const int tid = threadIdx.x;
    const int wave = tid >> 6, lane = tid & 63;
    const int bm = blockIdx.y * 128, bn = blockIdx.x * 128;
    const int wm = (wave >> 1) * 64, wn = (wave & 1) * 64;
    float4v acc[4][4] = {};

    const int srow = wave * 32 + (lane >> 2);
    const int skc = (lane & 3) * 8;
    const ushort* Ag = A + (size_t)(bm + srow) * lda + skc;
    const ushort* Bg = B + (size_t)(bn + srow) * ldb + skc;
    ushort* sAw = sA + (wave * 32) * 32;
    ushort* sBw = sB + (wave * 32) * 32;

    for (int k0 = 0; k0 < K; k0 += 32) {
        __builtin_amdgcn_global_load_lds((const AS1 void*)(Ag + k0), (AS3 void*)sAw, 16, 0, 0);
        __builtin_amdgcn_global_load_lds((const AS1 void*)(Ag + (size_t)16 * lda + k0),
                                         (AS3 void*)(sAw + 16 * 32), 16, 0, 0);
        __builtin_amdgcn_global_load_lds((const AS1 void*)(Bg + k0), (AS3 void*)sBw, 16, 0, 0);
        __builtin_amdgcn_global_load_lds((const AS1 void*)(Bg + (size_t)16 * ldb + k0),
                                         (AS3 void*)(sBw + 16 * 32), 16, 0, 0);
        __syncthreads();
        short8 af[4], bfr[4];
#pragma unroll
        for (int i = 0; i < 4; ++i) {
            af[i]  = *(const short8*)(sA + (wm + i * 16 + (lane & 15)) * 32 + (lane >> 4) * 8);
            bfr[i] = *(const short8*)(sB + (wn + i * 16 + (lane & 15)) * 32 + (lane >> 4) * 8);
        }
#pragma unroll
        for (int i = 0; i < 4; ++i)
#pragma unroll
            for (int j = 0; j < 4; ++j)
                acc[i][j] = __builtin_amdgcn_mfma_f32_16x16x32_bf16(af[i], bfr[j], acc[i][j], 0, 0, 0);
        __syncthreads();
    }
#pragma unroll
    for (int i = 0; i < 4; ++i) {
        int row0 = bm + wm + i * 16 + (lane >> 4) * 4;
#pragma unroll
        for (int j = 0; j < 4; ++j) {
            int col = bn + wn + j * 16 + (lane & 15);
            if (f32out) {
                float* C = (float*)Cv;
#pragma unroll
                for (int r = 0; r < 4; ++r)
                    C[(size_t)(row0 + r) * ldc + col] = acc[i][j][r];
            } else {
                ushort* C = (ushort*)Cv;
#pragma unroll
                for (int r = 0; r < 4; ++r)
                    C[(size_t)(row0 + r) * ldc + col] = f2b(acc[i][j][r]);
            }
        }
    }
}

// ---------- rmsnorm (in-place, one block per row, strided) ----------
__global__ void rmsnorm_inplace(ushort* __restrict__ d, const float* __restrict__ w,
                                int cols, int ld) {
    int row = blockIdx.x, tid = threadIdx.x;
    ushort* p = d + (size_t)row * ld;
    float ss = 0.f;
    for (int i = tid; i < cols; i += 256) { float v = b2f(p[i]); ss += v * v; }
#pragma unroll
    for (int off = 32; off >= 1; off >>= 1) ss += __shfl_xor(ss, off);
    __shared__ float red[4];
    if ((tid & 63) == 0) red[tid >> 6] = ss;
    __syncthreads();
    float tot = red[0] + red[1] + red[2] + red[3];
    float rs = rsqrtf(tot / (float)cols + 1e-6f);
    for (int i = tid; i < cols; i += 256) p[i] = f2b(b2f(p[i]) * rs * w[i]);
}

// ---------- kv norm (cols 0..512) + k_pe rope (cols 512..576), strided ----------
__global__ void kvnorm_rope(const ushort* __restrict__ kvraw, const float* __restrict__ w,
                            const float* __restrict__ freqs, ushort* __restrict__ kvc,
                            ushort* __restrict__ kpe, int ld) {
    int row = blockIdx.x, tid = threadIdx.x;
    int s = row & 2047;
    const ushort* p = kvraw + (size_t)row * ld;
    float v0 = b2f(p[tid]), v1 = b2f(p[tid + 256]);
    float ss = v0 * v0 + v1 * v1;
#pragma unroll
    for (int off = 32; off >= 1; off >>= 1) ss += __shfl_xor(ss, off);
    __shared__ float red[4];
    if ((tid & 63) == 0) red[tid >> 6] = ss;
    __syncthreads();
    float tot = red[0] + red[1] + red[2] + red[3];
    float rs = rsqrtf(tot / 512.f + 1e-6f);
    kvc[(size_t)row * 512 + tid] = f2b(v0 * rs * w[tid]);
    kvc[(size_t)row * 512 + tid + 256] = f2b(v1 * rs * w[tid + 256]);
    if (tid < 32) {
        float re = b2f(p[512 + 2 * tid]), im = b2f(p[512 + 2 * tid + 1]);
        float cs = freqs[(s * 32 + tid) * 2], sn = freqs[(s * 32 + tid) * 2 + 1];
        kpe[(size_t)row * 64 + 2 * tid] = f2b(re * cs - im * sn);
        kpe[(size_t)row * 64 + 2 * tid + 1] = f2b(re * sn + im * cs);
    }
}

// ---------- rope on q_pe (last 64 of each 192-dim head) ----------
__global__ void qrope(ushort* __restrict__ q, const float* __restrict__ freqs) {
    int idx = blockIdx.x * 256 + threadIdx.x;
    int i = idx & 31;
    int h = (idx >> 5) & 15;
    int srow = idx >> 9;
    int s = srow & 2047;
    ushort* p = q + ((size_t)srow * 16 + h) * 192 + 128 + 2 * i;
    float re = b2f(p[0]), im = b2f(p[1]);
    float cs = freqs[(s * 32 + i) * 2], sn = freqs[(s * 32 + i) * 2 + 1];
    p[0] = f2b(re * cs - im * sn);
    p[1] = f2b(re * sn + im * cs);
}

// ---------- K repack: Kfull[b][h][s][200] = k_nope(128) | k_pe(64) | pad(8) ----------
__global__ void k_repack(const ushort* __restrict__ kvb, const ushort* __restrict__ kpe,
                         ushort* __restrict__ Kfull) {
    int tid = threadIdx.x;
    int row = blockIdx.x * 8 + (tid >> 5);   // row = bh*2048 + s
    int c = tid & 31;
    int bh = row >> 11, s = row & 2047;
    int b = bh >> 4, h = bh & 15;
    size_t sg = (size_t)b * 2048 + s;
    short8 v = {0, 0, 0, 0, 0, 0, 0, 0};
    if (c < 16)      v = *(const short8*)(kvb + sg * 4096 + h * 256 + c * 8);
    else if (c < 24) v = *(const short8*)(kpe + sg * 64 + (c - 16) * 8);
    if (c < 25) *(short8*)(Kfull + (size_t)row * 200 + c * 8) = v;
}

// ---------- V repack/transpose: Vt[bh][kt][128][72] (cols 64..71 pad) ----------
__global__ __launch_bounds__(256)
void v_repack(const ushort* __restrict__ kvb, ushort* __restrict__ Vt) {
    __shared__ ushort sT[64][136];
    int tid = threadIdx.x;
    int kt = blockIdx.x, bh = blockIdx.y;
    int b = bh >> 4, h = bh & 15;
#pragma unroll
    for (int k = 0; k < 4; ++k) {
        int id = k * 256 + tid;
        int r = id >> 4, c8 = id & 15;
        size_t sg = (size_t)b * 2048 + kt * 64 + r;
        *(short8*)(&sT[r][c8 * 8]) = *(const short8*)(kvb + sg * 4096 + h * 256 + 128 + c8 * 8);
    }
    __syncthreads();
    int d = tid >> 1, half = tid & 1;
    ushort tmp[32];
#pragma unroll
    for (int i = 0; i < 32; ++i) tmp[i] = sT[half * 32 + i][d];
    ushort* dst = Vt + (((size_t)bh * 32 + kt) * 128 + d) * 72 + half * 32;
#pragma unroll
    for (int i = 0; i < 4; ++i) *(short8*)(dst + i * 8) = *(const short8*)(tmp + i * 8);
}

// ---------- causal flash attention, BQ=128, BKV=64 ----------
// grid (16 q-tiles longest-first, 32 bh), 256 threads, 2 blocks/CU.
// Wave w owns q rows [qt*128 + w*32, +32) as two 16-row MFMA groups g=0,1.
// Halves K/V staging traffic vs BQ=64 (each staged tile serves 128 q rows).
__global__ __launch_bounds__(256, 2)
void mla_attn4(const ushort* __restrict__ q, const ushort* __restrict__ Kfull,
               const ushort* __restrict__ Vt, ushort* __restrict__ out, float scale) {
    __shared__ ushort sK[64 * 200];
    __shared__ ushort sV[128 * 72];
    __shared__ ushort sP[4 * 32 * 72];   // per-wave 32 q-rows x 64 kv (+8 pad)
    const int tid = threadIdx.x, wave = tid >> 6, lane = tid & 63;
    const int lq = lane & 15, quad = lane >> 4;
    const int qt = 15 - blockIdx.x;       // longest-first
    const int bh = blockIdx.y;
    const int b = bh >> 4, h = bh & 15;
    const ushort* Kb = Kfull + (size_t)bh * 2048 * 200;
    const ushort* Vb = Vt + (size_t)bh * 32 * 128 * 72;

    short8 qf[2][6];
#pragma unroll
    for (int g = 0; g < 2; ++g) {
        int qrow = qt * 128 + (wave * 2 + g) * 16 + lq;
        const ushort* qp = q + ((size_t)(b * 2048 + qrow) * 16 + h) * 192 + quad * 8;
#pragma unroll
        for (int c = 0; c < 6; ++c) qf[g][c] = *(const short8*)(qp + c * 32);
    }

    float4v oacc[2][8] = {};
    float m_i[2][4], l_i[2][4];
#pragma unroll
    for (int g = 0; g < 2; ++g)
#pragma unroll
        for (int r = 0; r < 4; ++r) { m_i[g][r] = -INFINITY; l_i[g][r] = 0.f; }

    const int nkt = 2 * qt + 2;
    for (int kt = 0; kt < nkt; ++kt) {
        const ushort* Ksrc = Kb + (size_t)kt * 64 * 200;
        const ushort* Vsrc = Vb + (size_t)kt * 128 * 72;
#pragma unroll
        for (int i = 0; i < 7; ++i) {
            int s0 = i * 256 + wave * 64;
            if (s0 < 1600)
                __builtin_amdgcn_global_load_lds((const AS1 void*)(Ksrc + (size_t)(s0 + lane) * 8),
                                                 (AS3 void*)(sK + s0 * 8), 16, 0, 0);
        }
#pragma unroll
        for (int i = 0; i < 5; ++i) {
            int s0 = i * 256 + wave * 64;
            if (s0 < 1152)
                __builtin_amdgcn_global_load_lds((const AS1 void*)(Vsrc + (size_t)(s0 + lane) * 8),
                                                 (AS3 void*)(sV + s0 * 8), 16, 0, 0);
        }
        __syncthreads();
        // S = Q K^T : per wave 32 q-rows x 64 kv. kf shared across both g groups.
        float4v sc[2][4];
#pragma unroll
        for (int ct = 0; ct < 4; ++ct) {
            float4v a0 = {0.f, 0.f, 0.f, 0.f}, a1 = {0.f, 0.f, 0.f, 0.f};
#pragma unroll
            for (int c = 0; c < 6; ++c) {
                short8 kf = *(const short8*)(sK + (ct * 16 + lq) * 200 + c * 32 + quad * 8);
                a0 = __builtin_amdgcn_mfma_f32_16x16x32_bf16(qf[0][c], kf, a0, 0, 0, 0);
                a1 = __builtin_amdgcn_mfma_f32_16x16x32_bf16(qf[1][c], kf, a1, 0, 0, 0);
            }
            sc[0][ct] = a0;
            sc[1][ct] = a1;
        }
        // scale + causal mask + online softmax (rows = quad*4+r per group)
        const int edge = ((kt >> 1) == qt);
#pragma unroll
        for (int g = 0; g < 2; ++g) {
            const int myrow0 = qt * 128 + (wave * 2 + g) * 16 + quad * 4;
            float mnew[4];
#pragma unroll
            for (int r = 0; r < 4; ++r) mnew[r] = m_i[g][r];
#pragma unroll
            for (int ct = 0; ct < 4; ++ct)
#pragma unroll
                for (int r = 0; r < 4; ++r) {
                    float v = sc[g][ct][r] * scale;
                    if (edge && (kt * 64 + ct * 16 + lq) > (myrow0 + r)) v = -INFINITY;
                    sc[g][ct][r] = v;
                    mnew[r] = fmaxf(mnew[r], v);
                }
#pragma unroll
            for (int off = 8; off >= 1; off >>= 1)
#pragma unroll
                for (int r = 0; r < 4; ++r) mnew[r] = fmaxf(mnew[r], __shfl_xor(mnew[r], off));
            float alpha[4], psum[4];
#pragma unroll
            for (int r = 0; r < 4; ++r) {
                alpha[r] = __expf(m_i[g][r] - mnew[r]);
                m_i[g][r] = mnew[r];
                psum[r] = 0.f;
            }
#pragma unroll
            for (int ct = 0; ct < 4; ++ct)
#pragma unroll
                for (int r = 0; r < 4; ++r) {
                    float pv = __expf(sc[g][ct][r] - mnew[r]);
                    psum[r] += pv;
                    sP[(wave * 32 + g * 16 + quad * 4 + r) * 72 + ct * 16 + lq] = f2b(pv);
                }
#pragma unroll
            for (int off = 8; off >= 1; off >>= 1)
#pragma unroll
                for (int r = 0; r < 4; ++r) psum[r] += __shfl_xor(psum[r], off);
#pragma unroll
            for (int r = 0; r < 4; ++r) l_i[g][r] = l_i[g][r] * alpha[r] + psum[r];
#pragma unroll
            for (int dt = 0; dt < 8; ++dt)
#pragma unroll
                for (int r = 0; r < 4; ++r) oacc[g][dt][r] *= alpha[r];
        }
        __syncthreads();
        // O += P @ V  (vf shared across both g groups)
#pragma unroll
        for (int kc = 0; kc < 2; ++kc) {
            short8 pf0 = *(const short8*)(sP + (wave * 32 + lq) * 72 + kc * 32 + quad * 8);
            short8 pf1 = *(const short8*)(sP + (wave * 32 + 16 + lq) * 72 + kc * 32 + quad * 8);
#pragma unroll
            for (int dt = 0; dt < 8; ++dt) {
                short8 vf = *(const short8*)(sV + (dt * 16 + lq) * 72 + kc * 32 + quad * 8);
                oacc[0][dt] = __builtin_amdgcn_mfma_f32_16x16x32_bf16(pf0, vf, oacc[0][dt], 0, 0, 0);
                oacc[1][dt] = __builtin_amdgcn_mfma_f32_16x16x32_bf16(pf1, vf, oacc[1][dt], 0, 0, 0);
            }
        }
        __syncthreads();
    }
#pragma unroll
    for (int g = 0; g < 2; ++g) {
        const int myrow0 = qt * 128 + (wave * 2 + g) * 16 + quad * 4;
#pragma unroll
        for (int dt = 0; dt < 8; ++dt) {
#pragma unroll
            for (int r = 0; r < 4; ++r) {
                out[((size_t)(b * 2048 + myrow0 + r) * 16 + h) * 128 + dt * 16 + lq] =
                    f2b(oacc[g][dt][r] / l_i[g][r]);
            }
        }
    }
}

// ---------- launch ----------
extern "C" void kernel_launch(void* const* d_in, const int* in_sizes, int n_in,
                              void* d_out, int out_size, void* d_ws, size_t ws_size,
                              hipStream_t stream) {
    const float* x     = (const float*)d_in[0];
    const float* freqs = (const float*)d_in[2];
    const float* wq_a  = (const float*)d_in[3];
    const float* qnw   = (const float*)d_in[4];
    const float* wq_b  = (const float*)d_in[5];
    const float* wkv_a = (const float*)d_in[6];
    const float* kvnw  = (const float*)d_in[7];
    const float* wkv_b = (const float*)d_in[8];
    const float* wo    = (const float*)d_in[9];

    char* ws = (char*)d_ws;
    size_t off = 0;
    auto alloc = [&](size_t n) { char* p = ws + off; off += (n + 255) & ~(size_t)255; return p; };
    ushort* xb    = (ushort*)alloc(4096ull * 2048 * 2);   // dead after fused a-gemm
    ushort* wqkva = (ushort*)alloc(2176ull * 2048 * 2);   // wq_a rows 0..1535, wkv_a rows 1536..2111, pad..2175
    ushort* wqbb  = (ushort*)alloc(3072ull * 1536 * 2);   // dead after q_b gemm
    ushort* wkvbb = (ushort*)alloc(4096ull * 512 * 2);    // dead after kv_b gemm
    ushort* wob   = (ushort*)alloc(2048ull * 2048 * 2);   // live until final gemm
    ushort* qakv  = (ushort*)alloc(4096ull * 2176 * 2);   // qa cols 0..1535 | kvraw cols 1536..2111
    ushort* kvc   = (ushort*)alloc(4096ull * 512 * 2);
    ushort* kpe   = (ushort*)alloc(4096ull * 64 * 2);
    ushort* qfull = (ushort*)alloc(4096ull * 3072 * 2);
    ushort* kvbuf = (ushort*)alloc(4096ull * 4096 * 2);
    ushort* attno = (ushort*)alloc(4096ull * 2048 * 2);
    if (off > ws_size) return;
    // Aliased late buffers over dead regions:
    // Kfull 26.2 MB over xb+wqkva+wqbb (35.1 MB); Vt 18.9 MB over qakv+kvc (22.0 MB).
    ushort* Kfull = (ushort*)xb;
    ushort* Vt = (ushort*)qakv;

    auto cvt = [&](const float* s, ushort* dd, int sr, int cols, size_t dtot) {
        int t4 = (int)(dtot / 4);
        cvt_pad<<<(t4 + 255) / 256, 256, 0, stream>>>(s, dd, sr, cols, t4);
    };
    cvt(x, xb, 4096, 2048, 4096ull * 2048);
    cvt(wq_a, wqkva, 1536, 2048, 1536ull * 2048);
    cvt(wkv_a, wqkva + 1536ull * 2048, 576, 2048, 640ull * 2048);
    cvt(wq_b, wqbb, 3072, 1536, 3072ull * 1536);
    cvt(wkv_b, wkvbb, 4096, 512, 4096ull * 512);
    cvt(wo, wob, 2048, 2048, 2048ull * 2048);

    // fused q_a + kv_a projection: [4096 x 2048] @ [2176 x 2048]^T
    gemm_bt<<<dim3(17, 32), 256, 0, stream>>>(xb, wqkva, qakv, 2048, 2048, 2048, 2176, 0);
    rmsnorm_inplace<<<4096, 256, 0, stream>>>(qakv, qnw, 1536, 2176);
    kvnorm_rope<<<4096, 256, 0, stream>>>(qakv + 1536, kvnw, freqs, kvc, kpe, 2176);
    gemm_bt<<<dim3(24, 32), 256, 0, stream>>>(qakv, wqbb, qfull, 1536, 2176, 1536, 3072, 0);
    qrope<<<8192, 256, 0, stream>>>(qfull, freqs);
    gemm_bt<<<dim3(32, 32), 256, 0, stream>>>(kvc, wkvbb, kvbuf, 512, 512, 512, 4096, 0);
    // ---- repack (xb/wqkva/wqbb and qakv/kvc are dead from here) ----
    k_repack<<<8192, 256, 0, stream>>>(kvbuf, kpe, Kfull);
    v_repack<<<dim3(32, 32), 256, 0, stream>>>(kvbuf, Vt);
    const float scale = 1.0f / sqrtf(192.0f);
    mla_attn4<<<dim3(16, 32), 256, 0, stream>>>(qfull, Kfull, Vt, attno, scale);
    gemm_bt<<<dim3(16, 32), 256, 0, stream>>>(attno, wob, (float*)d_out, 2048, 2048, 2048, 2048, 1);
}

// Round 6
// 509.211 us; speedup vs baseline: 1.1475x; 1.1475x over previous
//
#include <hip/hip_runtime.h>
#include <math.h>

typedef short short8 __attribute__((ext_vector_type(8)));
typedef float float4v __attribute__((ext_vector_type(4)));
#define AS1 __attribute__((address_space(1)))
#define AS3 __attribute__((address_space(3)))

__device__ __forceinline__ float b2f(ushort u) {
    unsigned v = ((unsigned)u) << 16; float f; __builtin_memcpy(&f, &v, 4); return f;
}
__device__ __forceinline__ ushort f2b(float f) {
    unsigned v; __builtin_memcpy(&v, &f, 4);
    unsigned r = (v + 0x7fffu + ((v >> 16) & 1u)) >> 16;
    return (ushort)r;
}

// ---------- fp32 -> bf16 convert (optional zero-pad rows) ----------
__global__ void cvt_pad(const float* __restrict__ src, ushort* __restrict__ dst,
                        int src_rows, int cols, int total4) {
    int i = blockIdx.x * 256 + threadIdx.x;
    if (i >= total4) return;
    size_t e = (size_t)i * 4;
    int r = (int)(e / (size_t)cols);
    ushort4 o;
    if (r < src_rows) {
        float4 v = *(const float4*)(src + e);
        o.x = f2b(v.x); o.y = f2b(v.y); o.z = f2b(v.z); o.w = f2b(v.w);
    } else {
        o.x = 0; o.y = 0; o.z = 0; o.w = 0;
    }
    *(ushort4*)(dst + e) = o;
}

// ---------- bf16 GEMM: C(MxN) = A(MxK) @ B(NxK)^T, strided ----------
// mode 0: bf16 C; mode 1: f32 C; mode 2: MLA kv scatter (Kf nope cols + Vt transposed V)
__global__ __launch_bounds__(256)
void gemm_bt(const ushort* __restrict__ A, const ushort* __restrict__ B,
             void* __restrict__ Cv, int K, int lda, int ldb, int ldc, int mode,
             ushort* __restrict__ Kf, ushort* __restrict__ Vtp) {
    __shared__ ushort sA[128 * 32];
    __shared__ ushort sB[128 * 32];
    const int tid = threadIdx.x;
    const int wave = tid >> 6, lane = tid & 63;
    const int bm = blockIdx.y * 128, bn = blockIdx.x * 128;
    const int wm = (wave >> 1) * 64, wn = (wave & 1) * 64;
    const int lq = lane & 15, quad = lane >> 4;
    float4v acc[4][4] = {};

    const int srow = wave * 32 + (lane >> 2);
    const int skc = (lane & 3) * 8;
    const ushort* Ag = A + (size_t)(bm + srow) * lda + skc;
    const ushort* Bg = B + (size_t)(bn + srow) * ldb + skc;
    ushort* sAw = sA + (wave * 32) * 32;
    ushort* sBw = sB + (wave * 32) * 32;

    for (int k0 = 0; k0 < K; k0 += 32) {
        __builtin_amdgcn_global_load_lds((const AS1 void*)(Ag + k0), (AS3 void*)sAw, 16, 0, 0);
        __builtin_amdgcn_global_load_lds((const AS1 void*)(Ag + (size_t)16 * lda + k0),
                                         (AS3 void*)(sAw + 16 * 32), 16, 0, 0);
        __builtin_amdgcn_global_load_lds((const AS1 void*)(Bg + k0), (AS3 void*)sBw, 16, 0, 0);
        __builtin_amdgcn_global_load_lds((const AS1 void*)(Bg + (size_t)16 * ldb + k0),
                                         (AS3 void*)(sBw + 16 * 32), 16, 0, 0);
        __syncthreads();
        short8 af[4], bfr[4];
#pragma unroll
        for (int i = 0; i < 4; ++i) {
            af[i]  = *(const short8*)(sA + (wm + i * 16 + lq) * 32 + quad * 8);
            bfr[i] = *(const short8*)(sB + (wn + i * 16 + lq) * 32 + quad * 8);
        }
#pragma unroll
        for (int i = 0; i < 4; ++i)
#pragma unroll
            for (int j = 0; j < 4; ++j)
                acc[i][j] = __builtin_amdgcn_mfma_f32_16x16x32_bf16(af[i], bfr[j], acc[i][j], 0, 0, 0);
        __syncthreads();
    }
#pragma unroll
    for (int i = 0; i < 4; ++i) {
        int row0 = bm + wm + i * 16 + quad * 4;
#pragma unroll
        for (int j = 0; j < 4; ++j) {
            int col = bn + wn + j * 16 + lq;
            if (mode == 0) {
                ushort* C = (ushort*)Cv;
#pragma unroll
                for (int r = 0; r < 4; ++r)
                    C[(size_t)(row0 + r) * ldc + col] = f2b(acc[i][j][r]);
            } else if (mode == 1) {
                float* C = (float*)Cv;
#pragma unroll
                for (int r = 0; r < 4; ++r)
                    C[(size_t)(row0 + r) * ldc + col] = acc[i][j][r];
            } else {
                // MLA kv scatter: col = h*256 + c; c<128 -> Kfull nope, else Vt transposed
                int h = col >> 8, c = col & 255;
                int bh = ((row0 >> 11) << 4) + h;
                if (c < 128) {
#pragma unroll
                    for (int r = 0; r < 4; ++r) {
                        int s = (row0 + r) & 2047;
                        Kf[((size_t)bh * 2048 + s) * 200 + c] = f2b(acc[i][j][r]);
                    }
                } else {
                    int d = c - 128;
                    int kt = (row0 & 2047) >> 6, kv = row0 & 63;
                    ushort4 o;
                    o.x = f2b(acc[i][j][0]); o.y = f2b(acc[i][j][1]);
                    o.z = f2b(acc[i][j][2]); o.w = f2b(acc[i][j][3]);
                    *(ushort4*)(Vtp + (((size_t)bh * 32 + kt) * 128 + d) * 72 + kv) = o;
                }
            }
        }
    }
}

// ---------- rmsnorm (in-place, one block per row, strided) ----------
__global__ void rmsnorm_inplace(ushort* __restrict__ d, const float* __restrict__ w,
                                int cols, int ld) {
    int row = blockIdx.x, tid = threadIdx.x;
    ushort* p = d + (size_t)row * ld;
    float ss = 0.f;
    for (int i = tid; i < cols; i += 256) { float v = b2f(p[i]); ss += v * v; }
#pragma unroll
    for (int off = 32; off >= 1; off >>= 1) ss += __shfl_xor(ss, off);
    __shared__ float red[4];
    if ((tid & 63) == 0) red[tid >> 6] = ss;
    __syncthreads();
    float tot = red[0] + red[1] + red[2] + red[3];
    float rs = rsqrtf(tot / (float)cols + 1e-6f);
    for (int i = tid; i < cols; i += 256) p[i] = f2b(b2f(p[i]) * rs * w[i]);
}

// ---------- kv norm (cols 0..512) + k_pe rope (cols 512..576), strided ----------
__global__ void kvnorm_rope(const ushort* __restrict__ kvraw, const float* __restrict__ w,
                            const float* __restrict__ freqs, ushort* __restrict__ kvc,
                            ushort* __restrict__ kpe, int ld) {
    int row = blockIdx.x, tid = threadIdx.x;
    int s = row & 2047;
    const ushort* p = kvraw + (size_t)row * ld;
    float v0 = b2f(p[tid]), v1 = b2f(p[tid + 256]);
    float ss = v0 * v0 + v1 * v1;
#pragma unroll
    for (int off = 32; off >= 1; off >>= 1) ss += __shfl_xor(ss, off);
    __shared__ float red[4];
    if ((tid & 63) == 0) red[tid >> 6] = ss;
    __syncthreads();
    float tot = red[0] + red[1] + red[2] + red[3];
    float rs = rsqrtf(tot / 512.f + 1e-6f);
    kvc[(size_t)row * 512 + tid] = f2b(v0 * rs * w[tid]);
    kvc[(size_t)row * 512 + tid + 256] = f2b(v1 * rs * w[tid + 256]);
    if (tid < 32) {
        float re = b2f(p[512 + 2 * tid]), im = b2f(p[512 + 2 * tid + 1]);
        float cs = freqs[(s * 32 + tid) * 2], sn = freqs[(s * 32 + tid) * 2 + 1];
        kpe[(size_t)row * 64 + 2 * tid] = f2b(re * cs - im * sn);
        kpe[(size_t)row * 64 + 2 * tid + 1] = f2b(re * sn + im * cs);
    }
}

// ---------- rope on q_pe (last 64 of each 192-dim head) ----------
__global__ void qrope(ushort* __restrict__ q, const float* __restrict__ freqs) {
    int idx = blockIdx.x * 256 + threadIdx.x;
    int i = idx & 31;
    int h = (idx >> 5) & 15;
    int srow = idx >> 9;
    int s = srow & 2047;
    ushort* p = q + ((size_t)srow * 16 + h) * 192 + 128 + 2 * i;
    float re = b2f(p[0]), im = b2f(p[1]);
    float cs = freqs[(s * 32 + i) * 2], sn = freqs[(s * 32 + i) * 2 + 1];
    p[0] = f2b(re * cs - im * sn);
    p[1] = f2b(re * sn + im * cs);
}

// ---------- fill roped k_pe into Kfull cols 128..191 (broadcast over h) ----------
__global__ void kpe_fill(const ushort* __restrict__ kpe, ushort* __restrict__ Kfull) {
    int tid = threadIdx.x;
    int row = blockIdx.x * 8 + (tid >> 5);   // row = bh*2048 + s
    int c = tid & 31;
    int bh = row >> 11, s = row & 2047, b = bh >> 4;
    ushort2 v;
    v.x = kpe[((size_t)b * 2048 + s) * 64 + 2 * c];
    v.y = kpe[((size_t)b * 2048 + s) * 64 + 2 * c + 1];
    *(ushort2*)(Kfull + (size_t)row * 200 + 128 + 2 * c) = v;
}

// ---------- causal flash attention, paired q-tiles (verified attn2 schedule) ----------
// grid (16 pairs, 32 bh). Block p: phase 0 -> qt=31-p, phase 1 -> qt=p (33 iters uniform).
// 2 barriers/iter: sP is wave-private (same-wave DS ops complete in order -> no mid barrier).
__global__ __launch_bounds__(256)
void mla_attn5(const ushort* __restrict__ q, const ushort* __restrict__ Kfull,
               const ushort* __restrict__ Vt, ushort* __restrict__ out, float scale) {
    __shared__ ushort sK[64 * 200];
    __shared__ ushort sV[128 * 72];
    __shared__ ushort sP[4][16][72];
    const int tid = threadIdx.x, wave = tid >> 6, lane = tid & 63;
    const int lq = lane & 15, quad = lane >> 4;
    const int p = blockIdx.x, bh = blockIdx.y;
    const int b = bh >> 4, h = bh & 15;
    const ushort* Kb = Kfull + (size_t)bh * 2048 * 200;
    const ushort* Vb = Vt + (size_t)bh * 32 * 128 * 72;

    for (int phase = 0; phase < 2; ++phase) {
        const int qt = (phase == 0) ? (31 - p) : p;
        const int qrow = qt * 64 + wave * 16 + lq;
        const ushort* qp = q + ((size_t)(b * 2048 + qrow) * 16 + h) * 192 + quad * 8;
        short8 qf[6];
#pragma unroll
        for (int c = 0; c < 6; ++c) qf[c] = *(const short8*)(qp + c * 32);

        float4v oacc[8] = {};
        float m_i[4] = {-INFINITY, -INFINITY, -INFINITY, -INFINITY};
        float l_i[4] = {0.f, 0.f, 0.f, 0.f};
        const int myrow0 = qt * 64 + wave * 16 + quad * 4;

        for (int kt = 0; kt <= qt; ++kt) {
            const ushort* Ksrc = Kb + (size_t)kt * 64 * 200;
            const ushort* Vsrc = Vb + (size_t)kt * 128 * 72;
#pragma unroll
            for (int i = 0; i < 7; ++i) {
                int s0 = i * 256 + wave * 64;
                if (s0 < 1600)
                    __builtin_amdgcn_global_load_lds((const AS1 void*)(Ksrc + (size_t)(s0 + lane) * 8),
                                                     (AS3 void*)(sK + s0 * 8), 16, 0, 0);
            }
#pragma unroll
            for (int i = 0; i < 5; ++i) {
                int s0 = i * 256 + wave * 64;
                if (s0 < 1152)
                    __builtin_amdgcn_global_load_lds((const AS1 void*)(Vsrc + (size_t)(s0 + lane) * 8),
                                                     (AS3 void*)(sV + s0 * 8), 16, 0, 0);
            }
            __syncthreads();
            // S = Q K^T (per wave: 16 x 64)
            float4v sc[4];
#pragma unroll
            for (int ct = 0; ct < 4; ++ct) {
                float4v a = {0.f, 0.f, 0.f, 0.f};
#pragma unroll
                for (int c = 0; c < 6; ++c) {
                    short8 kf = *(const short8*)(sK + (ct * 16 + lq) * 200 + c * 32 + quad * 8);
                    a = __builtin_amdgcn_mfma_f32_16x16x32_bf16(qf[c], kf, a, 0, 0, 0);
                }
                sc[ct] = a;
            }
            // scale + causal mask + online softmax
            float mnew[4];
#pragma unroll
            for (int r = 0; r < 4; ++r) mnew[r] = m_i[r];
#pragma unroll
            for (int ct = 0; ct < 4; ++ct)
#pragma unroll
                for (int r = 0; r < 4; ++r) {
                    float v = sc[ct][r] * scale;
                    if (kt == qt && (kt * 64 + ct * 16 + lq) > (myrow0 + r)) v = -INFINITY;
                    sc[ct][r] = v;
                    mnew[r] = fmaxf(mnew[r], v);
                }
#pragma unroll
            for (int off = 8; off >= 1; off >>= 1)
#pragma unroll
                for (int r = 0; r < 4; ++r) mnew[r] = fmaxf(mnew[r], __shfl_xor(mnew[r], off));
            float alpha[4], psum[4];
#pragma unroll
            for (int r = 0; r < 4; ++r) {
                alpha[r] = __expf(m_i[r] - mnew[r]);
                m_i[r] = mnew[r];
                psum[r] = 0.f;
            }
#pragma unroll
            for (int ct = 0; ct < 4; ++ct)
#pragma unroll
                for (int r = 0; r < 4; ++r) {
                    float pv = __expf(sc[ct][r] - mnew[r]);
                    psum[r] += pv;
                    sP[wave][quad * 4 + r][ct * 16 + lq] = f2b(pv);
                }
#pragma unroll
            for (int off = 8; off >= 1; off >>= 1)
#pragma unroll
                for (int r = 0; r < 4; ++r) psum[r] += __shfl_xor(psum[r], off);
#pragma unroll
            for (int r = 0; r < 4; ++r) l_i[r] = l_i[r] * alpha[r] + psum[r];
#pragma unroll
            for (int dt = 0; dt < 8; ++dt)
#pragma unroll
                for (int r = 0; r < 4; ++r) oacc[dt][r] *= alpha[r];
            // O += P @ V  (sP is wave-private: same-wave DS order suffices, no barrier)
#pragma unroll
            for (int kc = 0; kc < 2; ++kc) {
                short8 pf = *(const short8*)(&sP[wave][lq][kc * 32 + quad * 8]);
#pragma unroll
                for (int dt = 0; dt < 8; ++dt) {
                    short8 vf = *(const short8*)(sV + (dt * 16 + lq) * 72 + kc * 32 + quad * 8);
                    oacc[dt] = __builtin_amdgcn_mfma_f32_16x16x32_bf16(pf, vf, oacc[dt], 0, 0, 0);
                }
            }
            __syncthreads();
        }
        float inv[4];
#pragma unroll
        for (int r = 0; r < 4; ++r) inv[r] = 1.f / l_i[r];
#pragma unroll
        for (int dt = 0; dt < 8; ++dt) {
#pragma unroll
            for (int r = 0; r < 4; ++r) {
                out[((size_t)(b * 2048 + myrow0 + r) * 16 + h) * 128 + dt * 16 + lq] =
                    f2b(oacc[dt][r] * inv[r]);
            }
        }
    }
}

// ---------- launch ----------
extern "C" void kernel_launch(void* const* d_in, const int* in_sizes, int n_in,
                              void* d_out, int out_size, void* d_ws, size_t ws_size,
                              hipStream_t stream) {
    const float* x     = (const float*)d_in[0];
    const float* freqs = (const float*)d_in[2];
    const float* wq_a  = (const float*)d_in[3];
    const float* qnw   = (const float*)d_in[4];
    const float* wq_b  = (const float*)d_in[5];
    const float* wkv_a = (const float*)d_in[6];
    const float* kvnw  = (const float*)d_in[7];
    const float* wkv_b = (const float*)d_in[8];
    const float* wo    = (const float*)d_in[9];

    char* ws = (char*)d_ws;
    size_t off = 0;
    auto alloc = [&](size_t n) { char* p = ws + off; off += (n + 255) & ~(size_t)255; return p; };
    ushort* xb    = (ushort*)alloc(4096ull * 2048 * 2);   // dead after fused a-gemm
    ushort* wqkva = (ushort*)alloc(2176ull * 2048 * 2);   // dead after fused a-gemm
    ushort* wqbb  = (ushort*)alloc(3072ull * 1536 * 2);   // dead after q_b gemm
    ushort* wkvbb = (ushort*)alloc(4096ull * 512 * 2);    // live until kv_b gemm
    ushort* wob   = (ushort*)alloc(2048ull * 2048 * 2);   // live until final gemm
    ushort* qakv  = (ushort*)alloc(4096ull * 2176 * 2);   // dead after q_b gemm
    ushort* kvc   = (ushort*)alloc(4096ull * 512 * 2);    // live until kv_b gemm
    ushort* kpe   = (ushort*)alloc(4096ull * 64 * 2);
    ushort* qfull = (ushort*)alloc(4096ull * 3072 * 2);
    ushort* kvbuf = (ushort*)alloc(4096ull * 4096 * 2);   // hosts Kfull (26.2 <= 33.6 MB)
    ushort* attno = (ushort*)alloc(4096ull * 2048 * 2);
    if (off > ws_size) return;
    // Kfull[32][2048][200] in kvbuf region (no aliasing).
    ushort* Kfull = kvbuf;
    // Vt[32][32][128][72] = 18.9 MB over xb+wqkva (25.7 MB), both dead before kv_b gemm.
    ushort* Vt = xb;

    auto cvt = [&](const float* s, ushort* dd, int sr, int cols, size_t dtot) {
        int t4 = (int)(dtot / 4);
        cvt_pad<<<(t4 + 255) / 256, 256, 0, stream>>>(s, dd, sr, cols, t4);
    };
    cvt(x, xb, 4096, 2048, 4096ull * 2048);
    cvt(wq_a, wqkva, 1536, 2048, 1536ull * 2048);
    cvt(wkv_a, wqkva + 1536ull * 2048, 576, 2048, 640ull * 2048);
    cvt(wq_b, wqbb, 3072, 1536, 3072ull * 1536);
    cvt(wkv_b, wkvbb, 4096, 512, 4096ull * 512);
    cvt(wo, wob, 2048, 2048, 2048ull * 2048);

    // fused q_a + kv_a projection: [4096 x 2048] @ [2176 x 2048]^T
    gemm_bt<<<dim3(17, 32), 256, 0, stream>>>(xb, wqkva, qakv, 2048, 2048, 2048, 2176, 0, nullptr, nullptr);
    rmsnorm_inplace<<<4096, 256, 0, stream>>>(qakv, qnw, 1536, 2176);
    kvnorm_rope<<<4096, 256, 0, stream>>>(qakv + 1536, kvnw, freqs, kvc, kpe, 2176);
    gemm_bt<<<dim3(24, 32), 256, 0, stream>>>(qakv, wqbb, qfull, 1536, 2176, 1536, 3072, 0, nullptr, nullptr);
    qrope<<<8192, 256, 0, stream>>>(qfull, freqs);
    kpe_fill<<<8192, 256, 0, stream>>>(kpe, Kfull);
    // kv_b gemm with fused scatter epilogue: writes Kfull nope cols + transposed Vt
    // (xb/wqkva dead -> Vt region safe; qakv dead)
    gemm_bt<<<dim3(32, 32), 256, 0, stream>>>(kvc, wkvbb, nullptr, 512, 512, 512, 0, 2, Kfull, Vt);
    const float scale = 1.0f / sqrtf(192.0f);
    mla_attn5<<<dim3(16, 32), 256, 0, stream>>>(qfull, Kfull, Vt, attno, scale);
    gemm_bt<<<dim3(16, 32), 256, 0, stream>>>(attno, wob, (float*)d_out, 2048, 2048, 2048, 2048, 1, nullptr, nullptr);
}